// Round 1
// baseline (1168.033 us; speedup 1.0000x reference)
//
#include <hip/hip_runtime.h>
#include <cstdint>
#include <cstddef>

#define BB 4
#define TT 2048
#define DD 512
#define NEG_INF (-3.402823466e+38f)
#define POS_INF (3.402823466e+38f)

__device__ __forceinline__ float sigmoidf_(float x){ return 1.0f/(1.0f+expf(-x)); }

// ---------------- row 1/||h|| ----------------
__global__ __launch_bounds__(64) void k_rnorm(const float* __restrict__ h, float* __restrict__ rnorm){
  int row = blockIdx.x;
  const float* hr = h + (size_t)row*DD;
  int lane = threadIdx.x;
  float ss = 0.f;
  #pragma unroll
  for (int q=0;q<2;q++){
    float4 v = *(const float4*)&hr[lane*4 + q*256];
    ss += v.x*v.x + v.y*v.y + v.z*v.z + v.w*v.w;
  }
  #pragma unroll
  for (int off=32; off; off>>=1) ss += __shfl_xor(ss, off);
  if (lane==0) rnorm[row] = 1.0f / fmaxf(sqrtf(ss), 1e-12f);
}

// ---------------- sim = xn . xn^T (lower-tri tiles), fp32 SGEMM ----------------
__global__ __launch_bounds__(256) void k_sim(const float* __restrict__ h, const float* __restrict__ rnorm,
                                             float* __restrict__ sim, int b0){
  int is = blockIdx.x;           // s tile
  int jt = blockIdx.y;           // t tile
  if (is > jt) return;           // only s <= t tiles needed
  int bl = blockIdx.z;
  int b = b0 + bl;
  const float* hb = h + (size_t)b*TT*DD;
  const float* rn = rnorm + (size_t)b*TT;
  float* simb = sim + (size_t)bl*TT*TT;
  int t0 = jt*128, s0 = is*128;

  __shared__ float As[16][128];
  __shared__ float Bs[16][128];
  int tid = threadIdx.x;
  int tx = tid & 15, ty = tid >> 4;

  float acc[8][8];
  #pragma unroll
  for (int i=0;i<8;i++)
    #pragma unroll
    for (int j=0;j<8;j++) acc[i][j] = 0.f;

  for (int k0=0; k0<DD; k0+=16){
    #pragma unroll
    for (int q=0;q<2;q++){
      int slot = tid + q*256;
      int r = slot >> 2; int kq = (slot & 3) << 2;
      float4 v = *(const float4*)&hb[(size_t)(t0+r)*DD + k0 + kq];
      float ra = rn[t0+r];
      As[kq+0][r]=v.x*ra; As[kq+1][r]=v.y*ra; As[kq+2][r]=v.z*ra; As[kq+3][r]=v.w*ra;
      float4 w = *(const float4*)&hb[(size_t)(s0+r)*DD + k0 + kq];
      float rb = rn[s0+r];
      Bs[kq+0][r]=w.x*rb; Bs[kq+1][r]=w.y*rb; Bs[kq+2][r]=w.z*rb; Bs[kq+3][r]=w.w*rb;
    }
    __syncthreads();
    #pragma unroll
    for (int k=0;k<16;k++){
      float a[8], bv[8];
      #pragma unroll
      for (int i=0;i<8;i++) a[i]  = As[k][ty*8+i];
      #pragma unroll
      for (int j=0;j<8;j++) bv[j] = Bs[k][tx*8+j];
      #pragma unroll
      for (int i=0;i<8;i++)
        #pragma unroll
        for (int j=0;j<8;j++) acc[i][j] = fmaf(a[i], bv[j], acc[i][j]);
    }
    __syncthreads();
  }
  #pragma unroll
  for (int i=0;i<8;i++){
    int t = t0 + ty*8 + i;
    float* dst = simb + (size_t)t*TT + s0 + tx*8;
    float4 v0 = {acc[i][0],acc[i][1],acc[i][2],acc[i][3]};
    float4 v1 = {acc[i][4],acc[i][5],acc[i][6],acc[i][7]};
    *(float4*)dst = v0;
    *(float4*)(dst+4) = v1;
  }
}

// ---------------- per-row top-k (wave per row) ----------------
__global__ __launch_bounds__(256) void k_topk(const float* __restrict__ sim, int b0,
                                              int eff_sim, int eff_con,
                                              int* __restrict__ topidx, int* __restrict__ botidx,
                                              int* __restrict__ bcnt){
  int wid  = threadIdx.x >> 6;
  int lane = threadIdx.x & 63;
  int lrow = blockIdx.x*4 + wid;              // chunk-local row
  int bl = lrow / TT; int t = lrow % TT;
  int grow = (b0 + bl)*TT + t;                // global row
  const float* srow = sim + (size_t)lrow*TT;

  // per-lane sorted top-16 (val desc, idx asc)
  float lv[16]; int li[16];
  #pragma unroll
  for (int q=0;q<16;q++){ lv[q]=NEG_INF; li[q]=0x7fffffff; }
  for (int s=lane; s<t; s+=64){
    float v = srow[s];
    if (v > lv[15] || (v == lv[15] && s < li[15])){
      float cv=v; int ci=s;
      #pragma unroll
      for (int q=0;q<16;q++){
        bool take = (cv > lv[q]) || (cv == lv[q] && ci < li[q]);
        float tv=lv[q]; int ti=li[q];
        if (take){ lv[q]=cv; li[q]=ci; cv=tv; ci=ti; }
      }
    }
  }
  // 16 global extractions via 64-lane argmax butterfly
  int wtop[16];
  #pragma unroll
  for (int k=0;k<16;k++){
    float bv = lv[0]; int bi = li[0]; int blane = lane;
    #pragma unroll
    for (int off=32; off; off>>=1){
      float ov = __shfl_xor(bv, off);
      int   oi = __shfl_xor(bi, off);
      int   ol = __shfl_xor(blane, off);
      if (ov > bv || (ov == bv && oi < bi)){ bv=ov; bi=oi; blane=ol; }
    }
    wtop[k] = bi;
    bool iwin = (lane == blane);
    #pragma unroll
    for (int q=0;q<15;q++){ if (iwin){ lv[q]=lv[q+1]; li[q]=li[q+1]; } }
    if (iwin){ lv[15]=NEG_INF; li[15]=0x7fffffff; }
    if (lane==0) topidx[(size_t)grow*16 + k] = bi;
  }

  // bottom picks only exist when (T - t) < eff_con  (<=7 rows per batch)
  int need = eff_con - (TT - t);
  int cnt = 0;
  if (need > 0){
    float qv[8]; int qi[8];
    #pragma unroll
    for (int q=0;q<8;q++){ qv[q]=POS_INF; qi[q]=0x7fffffff; }
    for (int s=lane; s<t; s+=64){
      float v = srow[s];
      if (v < qv[7] || (v == qv[7] && s < qi[7])){
        float cv=v; int ci=s;
        #pragma unroll
        for (int q=0;q<8;q++){
          bool take = (cv < qv[q]) || (cv == qv[q] && ci < qi[q]);
          float tv=qv[q]; int ti=qi[q];
          if (take){ qv[q]=cv; qi[q]=ci; cv=tv; ci=ti; }
        }
      }
    }
    #pragma unroll
    for (int k=0;k<8;k++){
      float bv = qv[0]; int bi = qi[0]; int blane = lane;
      #pragma unroll
      for (int off=32; off; off>>=1){
        float ov = __shfl_xor(bv, off);
        int   oi = __shfl_xor(bi, off);
        int   ol = __shfl_xor(blane, off);
        if (ov < bv || (ov == bv && oi < bi)){ bv=ov; bi=oi; blane=ol; }
      }
      bool iwin = (lane == blane);
      #pragma unroll
      for (int q=0;q<7;q++){ if (iwin){ qv[q]=qv[q+1]; qi[q]=qi[q+1]; } }
      if (iwin){ qv[7]=POS_INF; qi[7]=0x7fffffff; }
      if (cnt < need && bi != 0x7fffffff){
        bool dup = false;
        #pragma unroll
        for (int j=0;j<16;j++) if (j < eff_sim && wtop[j] == bi) dup = true;
        if (!dup){
          if (lane==0) botidx[(size_t)grow*8 + cnt] = bi;
          cnt++;
        }
      }
    }
  }
  if (lane==0) bcnt[grow] = cnt;
}

// ---------------- aggregate + blend + gelu + momentum ----------------
__global__ __launch_bounds__(256) void k_agg(const float* __restrict__ hsrc, float* __restrict__ hdst,
                                             const int* __restrict__ topidx, const int* __restrict__ botidx,
                                             const int* __restrict__ bcnt,
                                             const float* __restrict__ gain, const float* __restrict__ bias,
                                             const float* __restrict__ log_mix, const float* __restrict__ log_alpha,
                                             const float* __restrict__ log_momentum, int r, int eff_sim){
  int row = blockIdx.x;
  int b = row >> 11; int t = row & (TT-1);
  int n_sim = min(eff_sim, t);
  int n_con = bcnt[row];
  float mix      = sigmoidf_(log_mix[r]);
  float alpha    = sigmoidf_(log_alpha[r]);
  float momentum = sigmoidf_(log_momentum[0]);
  const float* hb = hsrc + (size_t)b*TT*DD;

  __shared__ int sidx[16];
  __shared__ int scidx[8];
  if (threadIdx.x < 16) sidx[threadIdx.x]  = (threadIdx.x < n_sim) ? topidx[(size_t)row*16 + threadIdx.x] : 0;
  if (threadIdx.x < 8)  scidx[threadIdx.x] = (threadIdx.x < n_con) ? botidx[(size_t)row*8  + threadIdx.x] : 0;
  __syncthreads();

  #pragma unroll
  for (int e = threadIdx.x; e < DD; e += 256){
    float sp = 0.f;
    for (int j=0;j<n_sim;j++) sp += hb[(size_t)sidx[j]*DD + e];
    float sn = 0.f;
    for (int j=0;j<n_con;j++) sn += hb[(size_t)scidx[j]*DD + e];
    float mp = sp / (float)max(n_sim, 1);
    float mn = sn / (float)max(n_con, 1);
    float ctx = alpha*mp + (1.f-alpha)*mn;
    float hv = hsrc[(size_t)row*DD + e];
    float blended = mix*hv + (1.f-mix)*ctx;
    float u = blended*gain[e] + bias[e];
    float g = 0.5f*u*(1.0f + erff(u*0.7071067811865475f));
    hdst[(size_t)row*DD + e] = momentum*hv + (1.f-momentum)*g;
  }
}

// ---------------- out = (h - x) * scale ----------------
__global__ __launch_bounds__(256) void k_final(const float* __restrict__ hfin, const float* __restrict__ x,
                                               const float* __restrict__ log_scale, float* __restrict__ out, int n){
  float scale = log1pf(expf(log_scale[0])) + 0.01f;
  int i = blockIdx.x*256 + threadIdx.x;
  if (i < n) out[i] = (hfin[i] - x[i]) * scale;
}

extern "C" void kernel_launch(void* const* d_in, const int* in_sizes, int n_in,
                              void* d_out, int out_size, void* d_ws, size_t ws_size,
                              hipStream_t stream) {
  const float* x         = (const float*)d_in[0];
  const float* gain      = (const float*)d_in[1];
  const float* bias      = (const float*)d_in[2];
  const float* log_mix   = (const float*)d_in[3];
  const float* log_alpha = (const float*)d_in[4];
  const float* log_mom   = (const float*)d_in[5];
  const float* log_scale = (const float*)d_in[6];

  float* hA = (float*)d_out;              // ping-pong buffer A lives in d_out
  char* ws = (char*)d_ws;
  size_t off = 0;
  auto alloc = [&](size_t bytes){ void* p = ws + off; off += (bytes + 255) & ~(size_t)255; return p; };

  float* hB     = (float*)alloc((size_t)BB*TT*DD*4);
  float* rnorm  = (float*)alloc((size_t)BB*TT*4);
  int*   topidx = (int*)  alloc((size_t)BB*TT*16*4);
  int*   botidx = (int*)  alloc((size_t)BB*TT*8*4);
  int*   bcnt   = (int*)  alloc((size_t)BB*TT*4);

  size_t rem = (ws_size > off) ? (ws_size - off) : 0;
  int cb = (int)(rem / ((size_t)TT*TT*4));
  if (cb < 1) cb = 1;
  if (cb > BB) cb = BB;
  float* sim = (float*)alloc((size_t)cb*TT*TT*4);

  const int ks[3] = {4, 8, 16};
  const int kc[3] = {2, 4, 8};

  const float* hsrc = x;
  float* hdst = hB;
  for (int r = 0; r < 3; ++r){
    k_rnorm<<<BB*TT, 64, 0, stream>>>(hsrc, rnorm);
    for (int b0 = 0; b0 < BB; b0 += cb){
      int nb = (BB - b0 < cb) ? (BB - b0) : cb;
      dim3 g(16, 16, nb);
      k_sim<<<g, 256, 0, stream>>>(hsrc, rnorm, sim, b0);
      k_topk<<<nb*TT/4, 256, 0, stream>>>(sim, b0, ks[r], kc[r], topidx, botidx, bcnt);
    }
    k_agg<<<BB*TT, 256, 0, stream>>>(hsrc, hdst, topidx, botidx, bcnt,
                                     gain + (size_t)r*DD, bias + (size_t)r*DD,
                                     log_mix, log_alpha, log_mom, r, ks[r]);
    if (r == 0){ hsrc = hB; hdst = hA; }
    else if (r == 1){ hsrc = hA; hdst = hB; }
  }
  k_final<<<(BB*TT*DD)/256, 256, 0, stream>>>(hB, x, log_scale, (float*)d_out, BB*TT*DD);
}

// Round 2
// 1036.021 us; speedup vs baseline: 1.1274x; 1.1274x over previous
//
#include <hip/hip_runtime.h>
#include <cstdint>
#include <cstddef>

#define BB 4
#define TT 2048
#define DD 512
#define NEG_INF (-3.402823466e+38f)
#define POS_INF (3.402823466e+38f)
#define SPAD 136   // LDS row pad: bank = (2*(k)+r)%32 -> max 2-way on store/read

__device__ __forceinline__ float sigmoidf_(float x){ return 1.0f/(1.0f+expf(-x)); }

// ---------------- row 1/||h|| ----------------
__global__ __launch_bounds__(64) void k_rnorm(const float* __restrict__ h, float* __restrict__ rnorm){
  int row = blockIdx.x;
  const float* hr = h + (size_t)row*DD;
  int lane = threadIdx.x;
  float ss = 0.f;
  #pragma unroll
  for (int q=0;q<2;q++){
    float4 v = *(const float4*)&hr[lane*4 + q*256];
    ss += v.x*v.x + v.y*v.y + v.z*v.z + v.w*v.w;
  }
  #pragma unroll
  for (int off=32; off; off>>=1) ss += __shfl_xor(ss, off);
  if (lane==0) rnorm[row] = 1.0f / fmaxf(sqrtf(ss), 1e-12f);
}

// ---------------- sim = xn . xn^T, lower-tri packed tiles, fp32 SGEMM ----------------
// 128x128 tile, BK=32, 512 threads, 4x8 micro-tile (cols split 4+4).
__global__ __launch_bounds__(512) void k_sim(const float* __restrict__ h, const float* __restrict__ rnorm,
                                             float* __restrict__ sim, int b0){
  // unpack packed lower-tri tile index p -> (jt, is), is <= jt
  int p = blockIdx.x;
  int jt = (int)((sqrtf(8.0f*(float)p + 1.0f) - 1.0f)*0.5f);
  while ((jt+1)*(jt+2)/2 <= p) jt++;
  while (jt*(jt+1)/2 > p) jt--;
  int is = p - jt*(jt+1)/2;

  int bl = blockIdx.y;
  int b = b0 + bl;
  const float* hb = h + (size_t)b*TT*DD;
  const float* rn = rnorm + (size_t)b*TT;
  float* simb = sim + (size_t)bl*TT*TT;
  int t0 = jt*128, s0 = is*128;

  __shared__ float As[32][SPAD];
  __shared__ float Bs[32][SPAD];

  int tid = threadIdx.x;
  int tx = tid & 15, ty = tid >> 4;          // ty in 0..31

  // staging thread mapping: slot = tid + q*512; r = slot>>3 (0..127), kq = (slot&7)*4
  int rA0 = tid >> 3;          // q=0 row
  int rA1 = rA0 + 64;          // q=1 row
  int kq  = (tid & 7) << 2;

  float raA0 = rn[t0 + rA0], raA1 = rn[t0 + rA1];
  float rbB0 = rn[s0 + rA0], rbB1 = rn[s0 + rA1];

  const float* gA0 = &hb[(size_t)(t0 + rA0)*DD + kq];
  const float* gA1 = &hb[(size_t)(t0 + rA1)*DD + kq];
  const float* gB0 = &hb[(size_t)(s0 + rA0)*DD + kq];
  const float* gB1 = &hb[(size_t)(s0 + rA1)*DD + kq];

  float acc[4][8];
  #pragma unroll
  for (int i=0;i<4;i++)
    #pragma unroll
    for (int j=0;j<8;j++) acc[i][j] = 0.f;

  // prefetch tile 0
  float4 nA0 = *(const float4*)(gA0);
  float4 nA1 = *(const float4*)(gA1);
  float4 nB0 = *(const float4*)(gB0);
  float4 nB1 = *(const float4*)(gB1);

  #define STORE_LDS() do { \
    As[kq+0][rA0]=nA0.x*raA0; As[kq+1][rA0]=nA0.y*raA0; As[kq+2][rA0]=nA0.z*raA0; As[kq+3][rA0]=nA0.w*raA0; \
    As[kq+0][rA1]=nA1.x*raA1; As[kq+1][rA1]=nA1.y*raA1; As[kq+2][rA1]=nA1.z*raA1; As[kq+3][rA1]=nA1.w*raA1; \
    Bs[kq+0][rA0]=nB0.x*rbB0; Bs[kq+1][rA0]=nB0.y*rbB0; Bs[kq+2][rA0]=nB0.z*rbB0; Bs[kq+3][rA0]=nB0.w*rbB0; \
    Bs[kq+0][rA1]=nB1.x*rbB1; Bs[kq+1][rA1]=nB1.y*rbB1; Bs[kq+2][rA1]=nB1.z*rbB1; Bs[kq+3][rA1]=nB1.w*rbB1; \
  } while(0)

  #define COMPUTE() do { \
    _Pragma("unroll") \
    for (int k=0;k<32;k++){ \
      float4 a4 = *(const float4*)&As[k][ty*4]; \
      float4 b4l = *(const float4*)&Bs[k][tx*4]; \
      float4 b4h = *(const float4*)&Bs[k][64 + tx*4]; \
      float av[4] = {a4.x,a4.y,a4.z,a4.w}; \
      float bv[8] = {b4l.x,b4l.y,b4l.z,b4l.w,b4h.x,b4h.y,b4h.z,b4h.w}; \
      _Pragma("unroll") \
      for (int i=0;i<4;i++) \
        _Pragma("unroll") \
        for (int j=0;j<8;j++) acc[i][j] = fmaf(av[i], bv[j], acc[i][j]); \
    } \
  } while(0)

  STORE_LDS();
  __syncthreads();

  for (int k0 = 32; k0 < DD; k0 += 32){
    nA0 = *(const float4*)(gA0 + k0);
    nA1 = *(const float4*)(gA1 + k0);
    nB0 = *(const float4*)(gB0 + k0);
    nB1 = *(const float4*)(gB1 + k0);
    COMPUTE();
    __syncthreads();
    STORE_LDS();
    __syncthreads();
  }
  COMPUTE();

  #pragma unroll
  for (int i=0;i<4;i++){
    int t = t0 + ty*4 + i;
    float* dst = simb + (size_t)t*TT + s0;
    float4 v0 = {acc[i][0],acc[i][1],acc[i][2],acc[i][3]};
    float4 v1 = {acc[i][4],acc[i][5],acc[i][6],acc[i][7]};
    *(float4*)(dst + tx*4) = v0;
    *(float4*)(dst + 64 + tx*4) = v1;
  }
  #undef STORE_LDS
  #undef COMPUTE
}

// ---------------- per-row top-k (wave per row) ----------------
__global__ __launch_bounds__(256) void k_topk(const float* __restrict__ sim, int b0,
                                              int eff_sim, int eff_con,
                                              int* __restrict__ topidx, int* __restrict__ botidx,
                                              int* __restrict__ bcnt){
  int wid  = threadIdx.x >> 6;
  int lane = threadIdx.x & 63;
  int lrow = blockIdx.x*4 + wid;              // chunk-local row
  int bl = lrow / TT; int t = lrow % TT;
  int grow = (b0 + bl)*TT + t;                // global row
  const float* srow = sim + (size_t)lrow*TT;

  // per-lane sorted top-16 (val desc, idx asc)
  float lv[16]; int li[16];
  #pragma unroll
  for (int q=0;q<16;q++){ lv[q]=NEG_INF; li[q]=0x7fffffff; }
  for (int s=lane; s<t; s+=64){
    float v = srow[s];
    if (v > lv[15] || (v == lv[15] && s < li[15])){
      float cv=v; int ci=s;
      #pragma unroll
      for (int q=0;q<16;q++){
        bool take = (cv > lv[q]) || (cv == lv[q] && ci < li[q]);
        float tv=lv[q]; int ti=li[q];
        if (take){ lv[q]=cv; li[q]=ci; cv=tv; ci=ti; }
      }
    }
  }
  // 16 global extractions via 64-lane argmax butterfly
  int wtop[16];
  #pragma unroll
  for (int k=0;k<16;k++){
    float bv = lv[0]; int bi = li[0]; int blane = lane;
    #pragma unroll
    for (int off=32; off; off>>=1){
      float ov = __shfl_xor(bv, off);
      int   oi = __shfl_xor(bi, off);
      int   ol = __shfl_xor(blane, off);
      if (ov > bv || (ov == bv && oi < bi)){ bv=ov; bi=oi; blane=ol; }
    }
    wtop[k] = bi;
    bool iwin = (lane == blane);
    #pragma unroll
    for (int q=0;q<15;q++){ if (iwin){ lv[q]=lv[q+1]; li[q]=li[q+1]; } }
    if (iwin){ lv[15]=NEG_INF; li[15]=0x7fffffff; }
    if (lane==0) topidx[(size_t)grow*16 + k] = bi;
  }

  // bottom picks only exist when (T - t) < eff_con  (<=7 rows per batch)
  int need = eff_con - (TT - t);
  int cnt = 0;
  if (need > 0){
    float qv[8]; int qi[8];
    #pragma unroll
    for (int q=0;q<8;q++){ qv[q]=POS_INF; qi[q]=0x7fffffff; }
    for (int s=lane; s<t; s+=64){
      float v = srow[s];
      if (v < qv[7] || (v == qv[7] && s < qi[7])){
        float cv=v; int ci=s;
        #pragma unroll
        for (int q=0;q<8;q++){
          bool take = (cv < qv[q]) || (cv == qv[q] && ci < qi[q]);
          float tv=qv[q]; int ti=qi[q];
          if (take){ qv[q]=cv; qi[q]=ci; cv=tv; ci=ti; }
        }
      }
    }
    #pragma unroll
    for (int k=0;k<8;k++){
      float bv = qv[0]; int bi = qi[0]; int blane = lane;
      #pragma unroll
      for (int off=32; off; off>>=1){
        float ov = __shfl_xor(bv, off);
        int   oi = __shfl_xor(bi, off);
        int   ol = __shfl_xor(blane, off);
        if (ov < bv || (ov == bv && oi < bi)){ bv=ov; bi=oi; blane=ol; }
      }
      bool iwin = (lane == blane);
      #pragma unroll
      for (int q=0;q<7;q++){ if (iwin){ qv[q]=qv[q+1]; qi[q]=qi[q+1]; } }
      if (iwin){ qv[7]=POS_INF; qi[7]=0x7fffffff; }
      if (cnt < need && bi != 0x7fffffff){
        bool dup = false;
        #pragma unroll
        for (int j=0;j<16;j++) if (j < eff_sim && wtop[j] == bi) dup = true;
        if (!dup){
          if (lane==0) botidx[(size_t)grow*8 + cnt] = bi;
          cnt++;
        }
      }
    }
  }
  if (lane==0) bcnt[grow] = cnt;
}

// ---------------- aggregate + blend + gelu + momentum ----------------
__global__ __launch_bounds__(256) void k_agg(const float* __restrict__ hsrc, float* __restrict__ hdst,
                                             const int* __restrict__ topidx, const int* __restrict__ botidx,
                                             const int* __restrict__ bcnt,
                                             const float* __restrict__ gain, const float* __restrict__ bias,
                                             const float* __restrict__ log_mix, const float* __restrict__ log_alpha,
                                             const float* __restrict__ log_momentum, int r, int eff_sim){
  int row = blockIdx.x;
  int b = row >> 11; int t = row & (TT-1);
  int n_sim = min(eff_sim, t);
  int n_con = bcnt[row];
  float mix      = sigmoidf_(log_mix[r]);
  float alpha    = sigmoidf_(log_alpha[r]);
  float momentum = sigmoidf_(log_momentum[0]);
  const float* hb = hsrc + (size_t)b*TT*DD;

  __shared__ int sidx[16];
  __shared__ int scidx[8];
  if (threadIdx.x < 16) sidx[threadIdx.x]  = (threadIdx.x < n_sim) ? topidx[(size_t)row*16 + threadIdx.x] : 0;
  if (threadIdx.x < 8)  scidx[threadIdx.x] = (threadIdx.x < n_con) ? botidx[(size_t)row*8  + threadIdx.x] : 0;
  __syncthreads();

  #pragma unroll
  for (int e = threadIdx.x; e < DD; e += 256){
    float sp = 0.f;
    for (int j=0;j<n_sim;j++) sp += hb[(size_t)sidx[j]*DD + e];
    float sn = 0.f;
    for (int j=0;j<n_con;j++) sn += hb[(size_t)scidx[j]*DD + e];
    float mp = sp / (float)max(n_sim, 1);
    float mn = sn / (float)max(n_con, 1);
    float ctx = alpha*mp + (1.f-alpha)*mn;
    float hv = hsrc[(size_t)row*DD + e];
    float blended = mix*hv + (1.f-mix)*ctx;
    float u = blended*gain[e] + bias[e];
    float g = 0.5f*u*(1.0f + erff(u*0.7071067811865475f));
    hdst[(size_t)row*DD + e] = momentum*hv + (1.f-momentum)*g;
  }
}

// ---------------- out = (h - x) * scale ----------------
__global__ __launch_bounds__(256) void k_final(const float* __restrict__ hfin, const float* __restrict__ x,
                                               const float* __restrict__ log_scale, float* __restrict__ out, int n){
  float scale = log1pf(expf(log_scale[0])) + 0.01f;
  int i = blockIdx.x*256 + threadIdx.x;
  if (i < n) out[i] = (hfin[i] - x[i]) * scale;
}

extern "C" void kernel_launch(void* const* d_in, const int* in_sizes, int n_in,
                              void* d_out, int out_size, void* d_ws, size_t ws_size,
                              hipStream_t stream) {
  const float* x         = (const float*)d_in[0];
  const float* gain      = (const float*)d_in[1];
  const float* bias      = (const float*)d_in[2];
  const float* log_mix   = (const float*)d_in[3];
  const float* log_alpha = (const float*)d_in[4];
  const float* log_mom   = (const float*)d_in[5];
  const float* log_scale = (const float*)d_in[6];

  float* hA = (float*)d_out;              // ping-pong buffer A lives in d_out
  char* ws = (char*)d_ws;
  size_t off = 0;
  auto alloc = [&](size_t bytes){ void* p = ws + off; off += (bytes + 255) & ~(size_t)255; return p; };

  float* hB     = (float*)alloc((size_t)BB*TT*DD*4);
  float* rnorm  = (float*)alloc((size_t)BB*TT*4);
  int*   topidx = (int*)  alloc((size_t)BB*TT*16*4);
  int*   botidx = (int*)  alloc((size_t)BB*TT*8*4);
  int*   bcnt   = (int*)  alloc((size_t)BB*TT*4);

  size_t rem = (ws_size > off) ? (ws_size - off) : 0;
  int cb = (int)(rem / ((size_t)TT*TT*4));
  if (cb < 1) cb = 1;
  if (cb > BB) cb = BB;
  float* sim = (float*)alloc((size_t)cb*TT*TT*4);

  const int ks[3] = {4, 8, 16};
  const int kc[3] = {2, 4, 8};

  const float* hsrc = x;
  float* hdst = hB;
  for (int r = 0; r < 3; ++r){
    k_rnorm<<<BB*TT, 64, 0, stream>>>(hsrc, rnorm);
    for (int b0 = 0; b0 < BB; b0 += cb){
      int nb = (BB - b0 < cb) ? (BB - b0) : cb;
      dim3 g(136, nb);                      // packed lower-tri tiles
      k_sim<<<g, 512, 0, stream>>>(hsrc, rnorm, sim, b0);
      k_topk<<<nb*TT/4, 256, 0, stream>>>(sim, b0, ks[r], kc[r], topidx, botidx, bcnt);
    }
    k_agg<<<BB*TT, 256, 0, stream>>>(hsrc, hdst, topidx, botidx, bcnt,
                                     gain + (size_t)r*DD, bias + (size_t)r*DD,
                                     log_mix, log_alpha, log_mom, r, ks[r]);
    if (r == 0){ hsrc = hB; hdst = hA; }
    else if (r == 1){ hsrc = hA; hdst = hB; }
  }
  k_final<<<(BB*TT*DD)/256, 256, 0, stream>>>(hB, x, log_scale, (float*)d_out, BB*TT*DD);
}

// Round 3
// 903.944 us; speedup vs baseline: 1.2922x; 1.1461x over previous
//
#include <hip/hip_runtime.h>
#include <hip/hip_bf16.h>
#include <cstdint>
#include <cstddef>

#define BB 4
#define TT 2048
#define DD 512
#define NEG_INF (-3.402823466e+38f)
#define POS_INF (3.402823466e+38f)

typedef __attribute__((ext_vector_type(8))) short bf16x8;
typedef __attribute__((ext_vector_type(8))) unsigned short ushort8;
typedef __attribute__((ext_vector_type(4))) float f32x4;

__device__ __forceinline__ float sigmoidf_(float x){ return 1.0f/(1.0f+expf(-x)); }

__device__ __forceinline__ unsigned short f2bf(float x){
  __hip_bfloat16 b = __float2bfloat16(x);
  return *reinterpret_cast<unsigned short*>(&b);
}

// ---------------- rnorm + bf16 hi/lo split of xn ----------------
__global__ __launch_bounds__(64) void k_normsplit(const float* __restrict__ h, float* __restrict__ rnorm,
                                                  unsigned short* __restrict__ Xh, unsigned short* __restrict__ Xl){
  int row = blockIdx.x;
  const float* hr = h + (size_t)row*DD;
  int lane = threadIdx.x;
  float4 v0 = *(const float4*)&hr[lane*4];
  float4 v1 = *(const float4*)&hr[lane*4 + 256];
  float ss = v0.x*v0.x+v0.y*v0.y+v0.z*v0.z+v0.w*v0.w
           + v1.x*v1.x+v1.y*v1.y+v1.z*v1.z+v1.w*v1.w;
  #pragma unroll
  for (int off=32; off; off>>=1) ss += __shfl_xor(ss, off);
  float rn = 1.0f / fmaxf(sqrtf(ss), 1e-12f);
  if (lane==0) rnorm[row] = rn;

  float xs[8] = {v0.x,v0.y,v0.z,v0.w,v1.x,v1.y,v1.z,v1.w};
  unsigned short hb[8], lb[8];
  #pragma unroll
  for (int q=0;q<8;q++){
    float xn = xs[q]*rn;
    unsigned short hh = f2bf(xn);
    __hip_bfloat16 bh = *reinterpret_cast<__hip_bfloat16*>(&hh);
    float rem = xn - __bfloat162float(bh);
    hb[q] = hh; lb[q] = f2bf(rem);
  }
  ushort4 h0 = {hb[0],hb[1],hb[2],hb[3]}, h1 = {hb[4],hb[5],hb[6],hb[7]};
  ushort4 l0 = {lb[0],lb[1],lb[2],lb[3]}, l1 = {lb[4],lb[5],lb[6],lb[7]};
  *(ushort4*)&Xh[(size_t)row*DD + lane*4]       = h0;
  *(ushort4*)&Xh[(size_t)row*DD + lane*4 + 256] = h1;
  *(ushort4*)&Xl[(size_t)row*DD + lane*4]       = l0;
  *(ushort4*)&Xl[(size_t)row*DD + lane*4 + 256] = l1;
}

// ---------------- sim via MFMA bf16 3-pass split, 128x128 tile ----------------
__global__ __launch_bounds__(256) void k_sim(const unsigned short* __restrict__ Xh,
                                             const unsigned short* __restrict__ Xl,
                                             float* __restrict__ sim, int b0){
  int p = blockIdx.x;
  int jt = (int)((sqrtf(8.0f*(float)p + 1.0f) - 1.0f)*0.5f);
  while ((jt+1)*(jt+2)/2 <= p) jt++;
  while (jt*(jt+1)/2 > p) jt--;
  int is = p - jt*(jt+1)/2;

  int bl = blockIdx.y;
  size_t xoff = (size_t)(b0 + bl)*TT*DD;
  const unsigned short* XhB = Xh + xoff;
  const unsigned short* XlB = Xl + xoff;
  float* simb = sim + (size_t)bl*TT*TT;
  int t0 = jt*128, s0 = is*128;

  __shared__ __align__(16) short As[128*32];
  __shared__ __align__(16) short Bs[128*32];

  int tid = threadIdx.x, wave = tid>>6, lane = tid&63;
  int wr = wave>>1, wc = wave&1;

  int srow = tid>>2;            // staging row 0..63
  int sc8  = (tid&3)*8;         // staging col offset (8 bf16)

  f32x4 acc[4][4];
  #pragma unroll
  for (int m=0;m<4;m++)
    #pragma unroll
    for (int n=0;n<4;n++) acc[m][n] = (f32x4){0.f,0.f,0.f,0.f};

  ushort8 ra0, ra1, rb0, rb1;
  auto gload = [&](int s){
    int pass = s>>4; int kcol = (s&15)*32;
    const unsigned short* sA = (pass<2) ? XhB : XlB;
    const unsigned short* sB = (pass!=1) ? XhB : XlB;
    ra0 = *(const ushort8*)&sA[(size_t)(t0+srow)*DD + kcol + sc8];
    ra1 = *(const ushort8*)&sA[(size_t)(t0+srow+64)*DD + kcol + sc8];
    rb0 = *(const ushort8*)&sB[(size_t)(s0+srow)*DD + kcol + sc8];
    rb1 = *(const ushort8*)&sB[(size_t)(s0+srow+64)*DD + kcol + sc8];
  };

  gload(0);
  for (int s=0; s<48; ++s){
    __syncthreads();
    *(ushort8*)&As[srow*32 + sc8]      = ra0;
    *(ushort8*)&As[(srow+64)*32 + sc8] = ra1;
    *(ushort8*)&Bs[srow*32 + sc8]      = rb0;
    *(ushort8*)&Bs[(srow+64)*32 + sc8] = rb1;
    __syncthreads();
    if (s < 47) gload(s+1);

    int arow = wr*64 + (lane&15);
    int brow = wc*64 + (lane&15);
    int kb = (lane>>4)*8;
    bf16x8 af[4], bf[4];
    #pragma unroll
    for (int m=0;m<4;m++) af[m] = *(const bf16x8*)&As[(arow + m*16)*32 + kb];
    #pragma unroll
    for (int n=0;n<4;n++) bf[n] = *(const bf16x8*)&Bs[(brow + n*16)*32 + kb];
    #pragma unroll
    for (int m=0;m<4;m++)
      #pragma unroll
      for (int n=0;n<4;n++)
        acc[m][n] = __builtin_amdgcn_mfma_f32_16x16x32_bf16(af[m], bf[n], acc[m][n], 0, 0, 0);
  }

  #pragma unroll
  for (int m=0;m<4;m++){
    int t = t0 + wr*64 + m*16 + (lane>>4)*4;
    #pragma unroll
    for (int n=0;n<4;n++){
      int sc = s0 + wc*64 + n*16 + (lane&15);
      float* dst = simb + (size_t)t*TT + sc;
      #pragma unroll
      for (int j=0;j<4;j++) dst[(size_t)j*TT] = acc[m][n][j];
    }
  }
}

// ---------------- top-k with gap-check + exact fp32 rescore ----------------
template<int ESIM, int ECON>
__global__ __launch_bounds__(256) void k_topk(const float* __restrict__ sim, int b0,
                                              const float* __restrict__ h, const float* __restrict__ rnorm,
                                              int* __restrict__ topidx, int* __restrict__ botidx,
                                              int* __restrict__ bcnt){
  constexpr int DEPTH = ESIM + 8;
  constexpr float TAU = 5e-5f;
  int wid  = threadIdx.x >> 6;
  int lane = threadIdx.x & 63;
  int lrow = blockIdx.x*4 + wid;
  int bl = lrow >> 11; int t = lrow & (TT-1);
  int gb = b0 + bl;
  int grow = (gb << 11) | t;
  const float* srow = sim + (size_t)lrow*TT;
  const float* hb = h + ((size_t)gb)*TT*DD;
  const float* rnb = rnorm + (size_t)gb*TT;

  // per-lane top-DEPTH (val desc, idx asc)
  float lv[DEPTH]; int li[DEPTH];
  #pragma unroll
  for (int q=0;q<DEPTH;q++){ lv[q]=NEG_INF; li[q]=0x7fffffff; }
  for (int s=lane; s<t; s+=64){
    float v = srow[s];
    if (v > lv[DEPTH-1] || (v == lv[DEPTH-1] && s < li[DEPTH-1])){
      float cv=v; int ci=s;
      #pragma unroll
      for (int q=0;q<DEPTH;q++){
        bool take = (cv > lv[q]) || (cv == lv[q] && ci < li[q]);
        float tv=lv[q]; int ti=li[q];
        if (take){ lv[q]=cv; li[q]=ci; cv=tv; ci=ti; }
      }
    }
  }

  float cand_v[ESIM+8]; int cand_i[ESIM+8];
  #pragma unroll
  for (int k=0;k<ESIM+8;k++){ cand_v[k]=NEG_INF; cand_i[k]=0x7fffffff; }

  int E1 = min(t, ESIM+1);
  float bvA = NEG_INF, bvB = NEG_INF;
  #pragma unroll
  for (int k=0;k<ESIM+1;k++){
    if (k < E1){
      float bv = lv[0]; int bi = li[0]; int wl = lane;
      #pragma unroll
      for (int off=32; off; off>>=1){
        float ov=__shfl_xor(bv,off); int oi=__shfl_xor(bi,off); int ol=__shfl_xor(wl,off);
        if (ov>bv || (ov==bv && oi<bi)){ bv=ov; bi=oi; wl=ol; }
      }
      cand_v[k]=bv; cand_i[k]=bi;
      if (lane==wl){
        #pragma unroll
        for (int q=0;q<DEPTH-1;q++){ lv[q]=lv[q+1]; li[q]=li[q+1]; }
        lv[DEPTH-1]=NEG_INF; li[DEPTH-1]=0x7fffffff;
      }
      if (k==ESIM-1) bvA=bv;
      if (k==ESIM)   bvB=bv;
    }
  }

  int n_sim = min(ESIM, t);
  bool resc = (t > ESIM) && (bvA - bvB < TAU);
  int sidx[ESIM];
  #pragma unroll
  for (int k=0;k<ESIM;k++) sidx[k] = 0x7fffffff;

  float rt = rnb[t];
  const float* hq = hb + (size_t)t*DD;

  if (!resc){
    #pragma unroll
    for (int k=0;k<ESIM;k++) sidx[k] = cand_i[k];
  } else {
    int E2 = min(t, ESIM+8);
    #pragma unroll
    for (int k=ESIM+1;k<ESIM+8;k++){
      if (k < E2){
        float bv = lv[0]; int bi = li[0]; int wl = lane;
        #pragma unroll
        for (int off=32; off; off>>=1){
          float ov=__shfl_xor(bv,off); int oi=__shfl_xor(bi,off); int ol=__shfl_xor(wl,off);
          if (ov>bv || (ov==bv && oi<bi)){ bv=ov; bi=oi; wl=ol; }
        }
        cand_v[k]=bv; cand_i[k]=bi;
        if (lane==wl){
          #pragma unroll
          for (int q=0;q<DEPTH-1;q++){ lv[q]=lv[q+1]; li[q]=li[q+1]; }
          lv[DEPTH-1]=NEG_INF; li[DEPTH-1]=0x7fffffff;
        }
      }
    }
    float4 q0 = *(const float4*)&hq[lane*4];
    float4 q1 = *(const float4*)&hq[lane*4 + 256];
    float mval = NEG_INF; int midx = 0x7fffffff;
    #pragma unroll
    for (int j=0;j<ESIM+8;j++){
      if (j < E2){
        int idx = cand_i[j];
        const float* hc = hb + (size_t)idx*DD;
        float4 c0 = *(const float4*)&hc[lane*4];
        float4 c1 = *(const float4*)&hc[lane*4 + 256];
        float pp = q0.x*c0.x+q0.y*c0.y+q0.z*c0.z+q0.w*c0.w
                 + q1.x*c1.x+q1.y*c1.y+q1.z*c1.z+q1.w*c1.w;
        #pragma unroll
        for (int off=32; off; off>>=1) pp += __shfl_xor(pp, off);
        float ex = pp * rt * rnb[idx];
        if (lane == j){ mval = ex; midx = idx; }
      }
    }
    #pragma unroll
    for (int k=0;k<ESIM;k++){
      if (k < n_sim){
        float bv = mval; int bi = midx; int wl = lane;
        #pragma unroll
        for (int off=32; off; off>>=1){
          float ov=__shfl_xor(bv,off); int oi=__shfl_xor(bi,off); int ol=__shfl_xor(wl,off);
          if (ov>bv || (ov==bv && oi<bi)){ bv=ov; bi=oi; wl=ol; }
        }
        sidx[k] = bi;
        if (lane==wl) mval = NEG_INF;
      }
    }
  }
  #pragma unroll
  for (int k=0;k<ESIM;k++) if (k < n_sim && lane==0) topidx[(size_t)grow*16+k] = sidx[k];

  // ---- bottoms: only rows with t > TT - ECON ----
  int need = ECON - (TT - t);
  int cnt = 0;
  if (need > 0){
    constexpr int BD = ECON + 8;
    float qv[BD]; int qi[BD];
    #pragma unroll
    for (int q=0;q<BD;q++){ qv[q]=POS_INF; qi[q]=0x7fffffff; }
    for (int s=lane; s<t; s+=64){
      float v = srow[s];
      if (v < qv[BD-1] || (v == qv[BD-1] && s < qi[BD-1])){
        float cv=v; int ci=s;
        #pragma unroll
        for (int q=0;q<BD;q++){
          bool take = (cv < qv[q]) || (cv == qv[q] && ci < qi[q]);
          float tv=qv[q]; int ti=qi[q];
          if (take){ qv[q]=cv; qi[q]=ci; cv=tv; ci=ti; }
        }
      }
    }
    float bmv = POS_INF; int bmi = 0x7fffffff;
    float gA = POS_INF, gB = POS_INF;
    #pragma unroll
    for (int k=0;k<BD;k++){
      float bv = qv[0]; int bi = qi[0]; int wl = lane;
      #pragma unroll
      for (int off=32; off; off>>=1){
        float ov=__shfl_xor(bv,off); int oi=__shfl_xor(bi,off); int ol=__shfl_xor(wl,off);
        if (ov<bv || (ov==bv && oi<bi)){ bv=ov; bi=oi; wl=ol; }
      }
      if (lane==wl){
        #pragma unroll
        for (int q=0;q<BD-1;q++){ qv[q]=qv[q+1]; qi[q]=qi[q+1]; }
        qv[BD-1]=POS_INF; qi[BD-1]=0x7fffffff;
      }
      bool mem = false;
      #pragma unroll
      for (int j=0;j<ESIM;j++) if (j < n_sim && sidx[j]==bi) mem = true;
      if (!mem && bi != 0x7fffffff){
        if (lane == cnt){ bmv = bv; bmi = bi; }
        if (cnt == need-1) gA = bv;
        if (cnt == need)   gB = bv;
        cnt++;
      }
    }
    int cntT = cnt;
    bool rb = (gB < POS_INF) && (gB - gA < TAU);
    if (!rb){
      #pragma unroll
      for (int k=0;k<ECON;k++){
        if (k < need && k < cntT){
          int ib = __shfl(bmi, k);
          if (lane==0) botidx[(size_t)grow*8+k] = ib;
        }
      }
    } else {
      float4 q0 = *(const float4*)&hq[lane*4];
      float4 q1 = *(const float4*)&hq[lane*4 + 256];
      float emv = POS_INF; int emi = 0x7fffffff;
      #pragma unroll
      for (int j=0;j<BD;j++){
        if (j < cntT){
          int idx = __shfl(bmi, j);
          const float* hc = hb + (size_t)idx*DD;
          float4 c0 = *(const float4*)&hc[lane*4];
          float4 c1 = *(const float4*)&hc[lane*4 + 256];
          float pp = q0.x*c0.x+q0.y*c0.y+q0.z*c0.z+q0.w*c0.w
                   + q1.x*c1.x+q1.y*c1.y+q1.z*c1.z+q1.w*c1.w;
          #pragma unroll
          for (int off=32; off; off>>=1) pp += __shfl_xor(pp, off);
          float ex = pp * rt * rnb[idx];
          if (lane == j){ emv = ex; emi = idx; }
        }
      }
      #pragma unroll
      for (int k=0;k<ECON;k++){
        if (k < need && k < cntT){
          float bv = emv; int bi = emi; int wl = lane;
          #pragma unroll
          for (int off=32; off; off>>=1){
            float ov=__shfl_xor(bv,off); int oi=__shfl_xor(bi,off); int ol=__shfl_xor(wl,off);
            if (ov<bv || (ov==bv && oi<bi)){ bv=ov; bi=oi; wl=ol; }
          }
          if (lane==0) botidx[(size_t)grow*8+k] = bi;
          if (lane==wl) emv = POS_INF;
        }
      }
    }
    cnt = min(need, cntT);
  }
  if (lane==0) bcnt[grow] = cnt;
}

// ---------------- aggregate + blend + gelu + momentum ----------------
__global__ __launch_bounds__(256) void k_agg(const float* __restrict__ hsrc, float* __restrict__ hdst,
                                             const int* __restrict__ topidx, const int* __restrict__ botidx,
                                             const int* __restrict__ bcnt,
                                             const float* __restrict__ gain, const float* __restrict__ bias,
                                             const float* __restrict__ log_mix, const float* __restrict__ log_alpha,
                                             const float* __restrict__ log_momentum, int r, int eff_sim){
  int row = blockIdx.x;
  int b = row >> 11; int t = row & (TT-1);
  int n_sim = min(eff_sim, t);
  int n_con = bcnt[row];
  float mix      = sigmoidf_(log_mix[r]);
  float alpha    = sigmoidf_(log_alpha[r]);
  float momentum = sigmoidf_(log_momentum[0]);
  const float* hb = hsrc + (size_t)b*TT*DD;

  __shared__ int sidx[16];
  __shared__ int scidx[8];
  if (threadIdx.x < 16) sidx[threadIdx.x]  = (threadIdx.x < n_sim) ? topidx[(size_t)row*16 + threadIdx.x] : 0;
  if (threadIdx.x < 8)  scidx[threadIdx.x] = (threadIdx.x < n_con) ? botidx[(size_t)row*8  + threadIdx.x] : 0;
  __syncthreads();

  #pragma unroll
  for (int e = threadIdx.x; e < DD; e += 256){
    float sp = 0.f;
    for (int j=0;j<n_sim;j++) sp += hb[(size_t)sidx[j]*DD + e];
    float sn = 0.f;
    for (int j=0;j<n_con;j++) sn += hb[(size_t)scidx[j]*DD + e];
    float mp = sp / (float)max(n_sim, 1);
    float mn = sn / (float)max(n_con, 1);
    float ctx = alpha*mp + (1.f-alpha)*mn;
    float hv = hsrc[(size_t)row*DD + e];
    float blended = mix*hv + (1.f-mix)*ctx;
    float u = blended*gain[e] + bias[e];
    float g = 0.5f*u*(1.0f + erff(u*0.7071067811865475f));
    hdst[(size_t)row*DD + e] = momentum*hv + (1.f-momentum)*g;
  }
}

// ---------------- out = (h - x) * scale ----------------
__global__ __launch_bounds__(256) void k_final(const float* __restrict__ hfin, const float* __restrict__ x,
                                               const float* __restrict__ log_scale, float* __restrict__ out, int n){
  float scale = log1pf(expf(log_scale[0])) + 0.01f;
  int i = blockIdx.x*256 + threadIdx.x;
  if (i < n) out[i] = (hfin[i] - x[i]) * scale;
}

extern "C" void kernel_launch(void* const* d_in, const int* in_sizes, int n_in,
                              void* d_out, int out_size, void* d_ws, size_t ws_size,
                              hipStream_t stream) {
  const float* x         = (const float*)d_in[0];
  const float* gain      = (const float*)d_in[1];
  const float* bias      = (const float*)d_in[2];
  const float* log_mix   = (const float*)d_in[3];
  const float* log_alpha = (const float*)d_in[4];
  const float* log_mom   = (const float*)d_in[5];
  const float* log_scale = (const float*)d_in[6];

  float* hA = (float*)d_out;
  char* ws = (char*)d_ws;
  size_t off = 0;
  auto alloc = [&](size_t bytes){ void* p = ws + off; off += (bytes + 255) & ~(size_t)255; return p; };

  float*          hB     = (float*)alloc((size_t)BB*TT*DD*4);
  float*          rnorm  = (float*)alloc((size_t)BB*TT*4);
  int*            topidx = (int*)  alloc((size_t)BB*TT*16*4);
  int*            botidx = (int*)  alloc((size_t)BB*TT*8*4);
  int*            bcnt   = (int*)  alloc((size_t)BB*TT*4);
  unsigned short* Xh     = (unsigned short*)alloc((size_t)BB*TT*DD*2);
  unsigned short* Xl     = (unsigned short*)alloc((size_t)BB*TT*DD*2);

  size_t rem = (ws_size > off) ? (ws_size - off) : 0;
  int cb = (int)(rem / ((size_t)TT*TT*4));
  if (cb < 1) cb = 1;
  if (cb > BB) cb = BB;
  float* sim = (float*)alloc((size_t)cb*TT*TT*4);

  const float* hsrc = x;
  float* hdst = hB;
  const int ks[3] = {4, 8, 16};

  for (int r = 0; r < 3; ++r){
    k_normsplit<<<BB*TT, 64, 0, stream>>>(hsrc, rnorm, Xh, Xl);
    for (int b0 = 0; b0 < BB; b0 += cb){
      int nb = (BB - b0 < cb) ? (BB - b0) : cb;
      dim3 g(136, nb);
      k_sim<<<g, 256, 0, stream>>>(Xh, Xl, sim, b0);
      if (r == 0)      k_topk<4,2><<<nb*TT/4, 256, 0, stream>>>(sim, b0, hsrc, rnorm, topidx, botidx, bcnt);
      else if (r == 1) k_topk<8,4><<<nb*TT/4, 256, 0, stream>>>(sim, b0, hsrc, rnorm, topidx, botidx, bcnt);
      else             k_topk<16,8><<<nb*TT/4, 256, 0, stream>>>(sim, b0, hsrc, rnorm, topidx, botidx, bcnt);
    }
    k_agg<<<BB*TT, 256, 0, stream>>>(hsrc, hdst, topidx, botidx, bcnt,
                                     gain + (size_t)r*DD, bias + (size_t)r*DD,
                                     log_mix, log_alpha, log_mom, r, ks[r]);
    if (r == 0){ hsrc = hB; hdst = hA; }
    else if (r == 1){ hsrc = hA; hdst = hB; }
  }
  k_final<<<(BB*TT*DD)/256, 256, 0, stream>>>(hB, x, log_scale, (float*)d_out, BB*TT*DD);
}

// Round 4
// 779.388 us; speedup vs baseline: 1.4987x; 1.1598x over previous
//
#include <hip/hip_runtime.h>
#include <hip/hip_bf16.h>
#include <cstdint>
#include <cstddef>

#define BB 4
#define TT 2048
#define DD 512
#define NEG_INF (-3.402823466e+38f)
#define POS_INF (3.402823466e+38f)

typedef __attribute__((ext_vector_type(8))) short bf16x8;
typedef __attribute__((ext_vector_type(8))) unsigned short ushort8;
typedef __attribute__((ext_vector_type(4))) float f32x4;

__device__ __forceinline__ float sigmoidf_(float x){ return 1.0f/(1.0f+expf(-x)); }

__device__ __forceinline__ unsigned short f2bf(float x){
  __hip_bfloat16 b = __float2bfloat16(x);
  return *reinterpret_cast<unsigned short*>(&b);
}

// ---------------- rnorm + bf16 hi/lo split of xn ----------------
__global__ __launch_bounds__(64) void k_normsplit(const float* __restrict__ h, float* __restrict__ rnorm,
                                                  unsigned short* __restrict__ Xh, unsigned short* __restrict__ Xl){
  int row = blockIdx.x;
  const float* hr = h + (size_t)row*DD;
  int lane = threadIdx.x;
  float4 v0 = *(const float4*)&hr[lane*4];
  float4 v1 = *(const float4*)&hr[lane*4 + 256];
  float ss = v0.x*v0.x+v0.y*v0.y+v0.z*v0.z+v0.w*v0.w
           + v1.x*v1.x+v1.y*v1.y+v1.z*v1.z+v1.w*v1.w;
  #pragma unroll
  for (int off=32; off; off>>=1) ss += __shfl_xor(ss, off);
  float rn = 1.0f / fmaxf(sqrtf(ss), 1e-12f);
  if (lane==0) rnorm[row] = rn;

  float xs[8] = {v0.x,v0.y,v0.z,v0.w,v1.x,v1.y,v1.z,v1.w};
  unsigned short hb[8], lb[8];
  #pragma unroll
  for (int q=0;q<8;q++){
    float xn = xs[q]*rn;
    unsigned short hh = f2bf(xn);
    __hip_bfloat16 bh = *reinterpret_cast<__hip_bfloat16*>(&hh);
    float rem = xn - __bfloat162float(bh);
    hb[q] = hh; lb[q] = f2bf(rem);
  }
  ushort4 h0 = {hb[0],hb[1],hb[2],hb[3]}, h1 = {hb[4],hb[5],hb[6],hb[7]};
  ushort4 l0 = {lb[0],lb[1],lb[2],lb[3]}, l1 = {lb[4],lb[5],lb[6],lb[7]};
  *(ushort4*)&Xh[(size_t)row*DD + lane*4]       = h0;
  *(ushort4*)&Xh[(size_t)row*DD + lane*4 + 256] = h1;
  *(ushort4*)&Xl[(size_t)row*DD + lane*4]       = l0;
  *(ushort4*)&Xl[(size_t)row*DD + lane*4 + 256] = l1;
}

// ---------------- sim via MFMA bf16 3-pass split, 128x128 tile ----------------
__global__ __launch_bounds__(256) void k_sim(const unsigned short* __restrict__ Xh,
                                             const unsigned short* __restrict__ Xl,
                                             float* __restrict__ sim, int b0){
  int p = blockIdx.x;
  int jt = (int)((sqrtf(8.0f*(float)p + 1.0f) - 1.0f)*0.5f);
  while ((jt+1)*(jt+2)/2 <= p) jt++;
  while (jt*(jt+1)/2 > p) jt--;
  int is = p - jt*(jt+1)/2;

  int bl = blockIdx.y;
  size_t xoff = (size_t)(b0 + bl)*TT*DD;
  const unsigned short* XhB = Xh + xoff;
  const unsigned short* XlB = Xl + xoff;
  float* simb = sim + (size_t)bl*TT*TT;
  int t0 = jt*128, s0 = is*128;

  __shared__ __align__(16) short As[128*32];
  __shared__ __align__(16) short Bs[128*32];

  int tid = threadIdx.x, wave = tid>>6, lane = tid&63;
  int wr = wave>>1, wc = wave&1;

  int srow = tid>>2;            // staging row 0..63
  int sc8  = (tid&3)*8;         // staging col offset (8 bf16)

  f32x4 acc[4][4];
  #pragma unroll
  for (int m=0;m<4;m++)
    #pragma unroll
    for (int n=0;n<4;n++) acc[m][n] = (f32x4){0.f,0.f,0.f,0.f};

  ushort8 ra0, ra1, rb0, rb1;
  auto gload = [&](int s){
    int pass = s>>4; int kcol = (s&15)*32;
    const unsigned short* sA = (pass<2) ? XhB : XlB;
    const unsigned short* sB = (pass!=1) ? XhB : XlB;
    ra0 = *(const ushort8*)&sA[(size_t)(t0+srow)*DD + kcol + sc8];
    ra1 = *(const ushort8*)&sA[(size_t)(t0+srow+64)*DD + kcol + sc8];
    rb0 = *(const ushort8*)&sB[(size_t)(s0+srow)*DD + kcol + sc8];
    rb1 = *(const ushort8*)&sB[(size_t)(s0+srow+64)*DD + kcol + sc8];
  };

  gload(0);
  for (int s=0; s<48; ++s){
    __syncthreads();
    *(ushort8*)&As[srow*32 + sc8]      = ra0;
    *(ushort8*)&As[(srow+64)*32 + sc8] = ra1;
    *(ushort8*)&Bs[srow*32 + sc8]      = rb0;
    *(ushort8*)&Bs[(srow+64)*32 + sc8] = rb1;
    __syncthreads();
    if (s < 47) gload(s+1);

    int arow = wr*64 + (lane&15);
    int brow = wc*64 + (lane&15);
    int kb = (lane>>4)*8;
    bf16x8 af[4], bf[4];
    #pragma unroll
    for (int m=0;m<4;m++) af[m] = *(const bf16x8*)&As[(arow + m*16)*32 + kb];
    #pragma unroll
    for (int n=0;n<4;n++) bf[n] = *(const bf16x8*)&Bs[(brow + n*16)*32 + kb];
    #pragma unroll
    for (int m=0;m<4;m++)
      #pragma unroll
      for (int n=0;n<4;n++)
        acc[m][n] = __builtin_amdgcn_mfma_f32_16x16x32_bf16(af[m], bf[n], acc[m][n], 0, 0, 0);
  }

  #pragma unroll
  for (int m=0;m<4;m++){
    int t = t0 + wr*64 + m*16 + (lane>>4)*4;
    #pragma unroll
    for (int n=0;n<4;n++){
      int sc = s0 + wc*64 + n*16 + (lane&15);
      float* dst = simb + (size_t)t*TT + sc;
      #pragma unroll
      for (int j=0;j<4;j++) dst[(size_t)j*TT] = acc[m][n][j];
    }
  }
}

// ---------------- top-k: lean registers, wave-uniform state in LDS ----------------
template<int ESIM, int ECON>
__global__ __launch_bounds__(256, 2) void k_topk(const float* __restrict__ sim, int b0,
                                                 const float* __restrict__ h, const float* __restrict__ rnorm,
                                                 int* __restrict__ topidx, int* __restrict__ botidx,
                                                 int* __restrict__ bcnt){
  constexpr int D1 = ESIM + 1;       // primary per-lane depth
  constexpr int XD = 7;              // extra rescore candidates
  constexpr int NC = ESIM + 1 + XD;  // max candidates
  constexpr int BD = 12;             // bottom extraction depth
  constexpr float TAU = 5e-5f;

  __shared__ int s_cand[4][NC];
  __shared__ int s_sel[4][ESIM];
  __shared__ int s_bot[4][BD];

  int wid  = threadIdx.x >> 6;
  int lane = threadIdx.x & 63;
  int lrow = blockIdx.x*4 + wid;
  int bl = lrow >> 11; int t = lrow & (TT-1);
  int gb = b0 + bl;
  int grow = (gb << 11) | t;
  const float* srow = sim + (size_t)lrow*TT;
  const float* hb  = h + (size_t)gb*TT*DD;
  const float* rnb = rnorm + (size_t)gb*TT;

  // ---- primary scan: per-lane sorted top-D1 (val desc, idx asc) ----
  float lv[D1]; int li[D1];
  #pragma unroll
  for (int q=0;q<D1;q++){ lv[q]=NEG_INF; li[q]=0x7fffffff; }
  for (int s=lane; s<t; s+=64){
    float v = srow[s];
    if (v > lv[D1-1] || (v == lv[D1-1] && s < li[D1-1])){
      float cv=v; int ci=s;
      #pragma unroll
      for (int q=0;q<D1;q++){
        bool take = (cv > lv[q]) || (cv == lv[q] && ci < li[q]);
        float tv=lv[q]; int ti=li[q];
        if (take){ lv[q]=cv; li[q]=ci; cv=tv; ci=ti; }
      }
    }
  }

  int n_sim = min(ESIM, t);
  int E1 = min(t, D1);
  float bvA = NEG_INF, bvB = NEG_INF; int biB = 0x7fffffff;

  #pragma unroll
  for (int k=0;k<D1;k++){
    if (k < E1){
      float bv = lv[0]; int bi = li[0]; int wl = lane;
      #pragma unroll
      for (int off=32; off; off>>=1){
        float ov=__shfl_xor(bv,off); int oi=__shfl_xor(bi,off); int ol=__shfl_xor(wl,off);
        if (ov>bv || (ov==bv && oi<bi)){ bv=ov; bi=oi; wl=ol; }
      }
      if (lane==wl){
        #pragma unroll
        for (int q=0;q<D1-1;q++){ lv[q]=lv[q+1]; li[q]=li[q+1]; }
        lv[D1-1]=NEG_INF; li[D1-1]=0x7fffffff;
      }
      if (lane==0) s_cand[wid][k] = bi;
      if (k==ESIM-1) bvA = bv;
      if (k==ESIM){ bvB = bv; biB = bi; }
    }
  }

  bool resc = (t > ESIM) && (bvA - bvB < TAU);

  if (!resc){
    if (lane < n_sim) s_sel[wid][lane] = s_cand[wid][lane];
  } else {
    // ---- rare: second filtered scan for XD more candidates after (bvB,biB) ----
    float xv[XD]; int xi[XD];
    #pragma unroll
    for (int q=0;q<XD;q++){ xv[q]=NEG_INF; xi[q]=0x7fffffff; }
    for (int s=lane; s<t; s+=64){
      float v = srow[s];
      bool after = (v < bvB) || (v == bvB && s > biB);
      if (after && (v > xv[XD-1] || (v == xv[XD-1] && s < xi[XD-1]))){
        float cv=v; int ci=s;
        #pragma unroll
        for (int q=0;q<XD;q++){
          bool take = (cv > xv[q]) || (cv == xv[q] && ci < xi[q]);
          float tv=xv[q]; int ti=xi[q];
          if (take){ xv[q]=cv; xi[q]=ci; cv=tv; ci=ti; }
        }
      }
    }
    int E2 = min(t, NC);
    #pragma unroll
    for (int k=0;k<XD;k++){
      if (D1 + k < E2){
        float bv = xv[0]; int bi = xi[0]; int wl = lane;
        #pragma unroll
        for (int off=32; off; off>>=1){
          float ov=__shfl_xor(bv,off); int oi=__shfl_xor(bi,off); int ol=__shfl_xor(wl,off);
          if (ov>bv || (ov==bv && oi<bi)){ bv=ov; bi=oi; wl=ol; }
        }
        if (lane==wl){
          #pragma unroll
          for (int q=0;q<XD-1;q++){ xv[q]=xv[q+1]; xi[q]=xi[q+1]; }
          xv[XD-1]=NEG_INF; xi[XD-1]=0x7fffffff;
        }
        if (lane==0) s_cand[wid][D1 + k] = bi;
      }
    }
    int ncand = E2;
    // exact fp32 rescore of candidates
    float rt = rnb[t];
    const float* hq = hb + (size_t)t*DD;
    float4 q0 = *(const float4*)&hq[lane*4];
    float4 q1 = *(const float4*)&hq[lane*4 + 256];
    float mval = NEG_INF; int midx = 0x7fffffff;
    #pragma unroll
    for (int j=0;j<NC;j++){
      if (j < ncand){
        int idx = s_cand[wid][j];
        const float* hc = hb + (size_t)idx*DD;
        float4 c0 = *(const float4*)&hc[lane*4];
        float4 c1 = *(const float4*)&hc[lane*4 + 256];
        float pp = q0.x*c0.x+q0.y*c0.y+q0.z*c0.z+q0.w*c0.w
                 + q1.x*c1.x+q1.y*c1.y+q1.z*c1.z+q1.w*c1.w;
        #pragma unroll
        for (int off=32; off; off>>=1) pp += __shfl_xor(pp, off);
        float ex = pp * rt * rnb[idx];
        if (lane == j){ mval = ex; midx = idx; }
      }
    }
    #pragma unroll
    for (int k=0;k<ESIM;k++){
      if (k < n_sim){
        float bv = mval; int bi = midx; int wl = lane;
        #pragma unroll
        for (int off=32; off; off>>=1){
          float ov=__shfl_xor(bv,off); int oi=__shfl_xor(bi,off); int ol=__shfl_xor(wl,off);
          if (ov>bv || (ov==bv && oi<bi)){ bv=ov; bi=oi; wl=ol; }
        }
        if (lane==0) s_sel[wid][k] = bi;
        if (lane==wl) mval = NEG_INF;
      }
    }
  }
  if (lane < n_sim) topidx[(size_t)grow*16 + lane] = s_sel[wid][lane];

  // ---- bottoms: only rows with t > TT - ECON (<=7 per batch) ----
  int need = ECON - (TT - t);
  int cnt = 0;
  if (need > 0){
    float qv[BD]; int qi[BD];
    #pragma unroll
    for (int q=0;q<BD;q++){ qv[q]=POS_INF; qi[q]=0x7fffffff; }
    for (int s=lane; s<t; s+=64){
      float v = srow[s];
      if (v < qv[BD-1] || (v == qv[BD-1] && s < qi[BD-1])){
        float cv=v; int ci=s;
        #pragma unroll
        for (int q=0;q<BD;q++){
          bool take = (cv < qv[q]) || (cv == qv[q] && ci < qi[q]);
          float tv=qv[q]; int ti=qi[q];
          if (take){ qv[q]=cv; qi[q]=ci; cv=tv; ci=ti; }
        }
      }
    }
    float gA = POS_INF, gB = POS_INF;
    int want = min(need + 4, t - n_sim);
    #pragma unroll
    for (int k=0;k<BD;k++){
      float bv = qv[0]; int bi = qi[0]; int wl = lane;
      #pragma unroll
      for (int off=32; off; off>>=1){
        float ov=__shfl_xor(bv,off); int oi=__shfl_xor(bi,off); int ol=__shfl_xor(wl,off);
        if (ov<bv || (ov==bv && oi<bi)){ bv=ov; bi=oi; wl=ol; }
      }
      if (lane==wl){
        #pragma unroll
        for (int q=0;q<BD-1;q++){ qv[q]=qv[q+1]; qi[q]=qi[q+1]; }
        qv[BD-1]=POS_INF; qi[BD-1]=0x7fffffff;
      }
      bool valid = (bi != 0x7fffffff);
      bool dup = false;
      #pragma unroll
      for (int j=0;j<ESIM;j++) if (j < n_sim && s_sel[wid][j]==bi) dup = true;
      if (valid && !dup && cnt < want){
        if (lane==0) s_bot[wid][cnt] = bi;
        if (cnt == need-1) gA = bv;
        if (cnt == need)   gB = bv;
        cnt++;
      }
    }
    int npick = min(need, cnt);
    bool rb = (cnt > need) && (gB - gA < TAU);
    if (!rb){
      if (lane < npick) botidx[(size_t)grow*8 + lane] = s_bot[wid][lane];
    } else {
      float rt = rnb[t];
      const float* hq = hb + (size_t)t*DD;
      float4 q0 = *(const float4*)&hq[lane*4];
      float4 q1 = *(const float4*)&hq[lane*4 + 256];
      float emv = POS_INF; int emi = 0x7fffffff;
      #pragma unroll
      for (int j=0;j<BD;j++){
        if (j < cnt){
          int idx = s_bot[wid][j];
          const float* hc = hb + (size_t)idx*DD;
          float4 c0 = *(const float4*)&hc[lane*4];
          float4 c1 = *(const float4*)&hc[lane*4 + 256];
          float pp = q0.x*c0.x+q0.y*c0.y+q0.z*c0.z+q0.w*c0.w
                   + q1.x*c1.x+q1.y*c1.y+q1.z*c1.z+q1.w*c1.w;
          #pragma unroll
          for (int off=32; off; off>>=1) pp += __shfl_xor(pp, off);
          float ex = pp * rt * rnb[idx];
          if (lane == j){ emv = ex; emi = idx; }
        }
      }
      #pragma unroll
      for (int k=0;k<ECON;k++){
        if (k < npick){
          float bv = emv; int bi = emi; int wl = lane;
          #pragma unroll
          for (int off=32; off; off>>=1){
            float ov=__shfl_xor(bv,off); int oi=__shfl_xor(bi,off); int ol=__shfl_xor(wl,off);
            if (ov<bv || (ov==bv && oi<bi)){ bv=ov; bi=oi; wl=ol; }
          }
          if (lane==0) botidx[(size_t)grow*8 + k] = bi;
          if (lane==wl) emv = POS_INF;
        }
      }
    }
    cnt = npick;
  }
  if (lane==0) bcnt[grow] = cnt;
}

// ---------------- aggregate + blend + gelu + momentum ----------------
__global__ __launch_bounds__(256) void k_agg(const float* __restrict__ hsrc, float* __restrict__ hdst,
                                             const int* __restrict__ topidx, const int* __restrict__ botidx,
                                             const int* __restrict__ bcnt,
                                             const float* __restrict__ gain, const float* __restrict__ bias,
                                             const float* __restrict__ log_mix, const float* __restrict__ log_alpha,
                                             const float* __restrict__ log_momentum, int r, int eff_sim){
  int row = blockIdx.x;
  int b = row >> 11; int t = row & (TT-1);
  int n_sim = min(eff_sim, t);
  int n_con = bcnt[row];
  float mix      = sigmoidf_(log_mix[r]);
  float alpha    = sigmoidf_(log_alpha[r]);
  float momentum = sigmoidf_(log_momentum[0]);
  const float* hb = hsrc + (size_t)b*TT*DD;

  __shared__ int sidx[16];
  __shared__ int scidx[8];
  if (threadIdx.x < 16) sidx[threadIdx.x]  = (threadIdx.x < n_sim) ? topidx[(size_t)row*16 + threadIdx.x] : 0;
  if (threadIdx.x < 8)  scidx[threadIdx.x] = (threadIdx.x < n_con) ? botidx[(size_t)row*8  + threadIdx.x] : 0;
  __syncthreads();

  #pragma unroll
  for (int e = threadIdx.x; e < DD; e += 256){
    float sp = 0.f;
    for (int j=0;j<n_sim;j++) sp += hb[(size_t)sidx[j]*DD + e];
    float sn = 0.f;
    for (int j=0;j<n_con;j++) sn += hb[(size_t)scidx[j]*DD + e];
    float mp = sp / (float)max(n_sim, 1);
    float mn = sn / (float)max(n_con, 1);
    float ctx = alpha*mp + (1.f-alpha)*mn;
    float hv = hsrc[(size_t)row*DD + e];
    float blended = mix*hv + (1.f-mix)*ctx;
    float u = blended*gain[e] + bias[e];
    float g = 0.5f*u*(1.0f + erff(u*0.7071067811865475f));
    hdst[(size_t)row*DD + e] = momentum*hv + (1.f-momentum)*g;
  }
}

// ---------------- out = (h - x) * scale ----------------
__global__ __launch_bounds__(256) void k_final(const float* __restrict__ hfin, const float* __restrict__ x,
                                               const float* __restrict__ log_scale, float* __restrict__ out, int n){
  float scale = log1pf(expf(log_scale[0])) + 0.01f;
  int i = blockIdx.x*256 + threadIdx.x;
  if (i < n) out[i] = (hfin[i] - x[i]) * scale;
}

extern "C" void kernel_launch(void* const* d_in, const int* in_sizes, int n_in,
                              void* d_out, int out_size, void* d_ws, size_t ws_size,
                              hipStream_t stream) {
  const float* x         = (const float*)d_in[0];
  const float* gain      = (const float*)d_in[1];
  const float* bias      = (const float*)d_in[2];
  const float* log_mix   = (const float*)d_in[3];
  const float* log_alpha = (const float*)d_in[4];
  const float* log_mom   = (const float*)d_in[5];
  const float* log_scale = (const float*)d_in[6];

  float* hA = (float*)d_out;
  char* ws = (char*)d_ws;
  size_t off = 0;
  auto alloc = [&](size_t bytes){ void* p = ws + off; off += (bytes + 255) & ~(size_t)255; return p; };

  float*          hB     = (float*)alloc((size_t)BB*TT*DD*4);
  float*          rnorm  = (float*)alloc((size_t)BB*TT*4);
  int*            topidx = (int*)  alloc((size_t)BB*TT*16*4);
  int*            botidx = (int*)  alloc((size_t)BB*TT*8*4);
  int*            bcnt   = (int*)  alloc((size_t)BB*TT*4);
  unsigned short* Xh     = (unsigned short*)alloc((size_t)BB*TT*DD*2);
  unsigned short* Xl     = (unsigned short*)alloc((size_t)BB*TT*DD*2);

  size_t rem = (ws_size > off) ? (ws_size - off) : 0;
  int cb = (int)(rem / ((size_t)TT*TT*4));
  if (cb < 1) cb = 1;
  if (cb > BB) cb = BB;
  float* sim = (float*)alloc((size_t)cb*TT*TT*4);

  const float* hsrc = x;
  float* hdst = hB;
  const int ks[3] = {4, 8, 16};

  for (int r = 0; r < 3; ++r){
    k_normsplit<<<BB*TT, 64, 0, stream>>>(hsrc, rnorm, Xh, Xl);
    for (int b0 = 0; b0 < BB; b0 += cb){
      int nb = (BB - b0 < cb) ? (BB - b0) : cb;
      dim3 g(136, nb);
      k_sim<<<g, 256, 0, stream>>>(Xh, Xl, sim, b0);
      if (r == 0)      k_topk<4,2><<<nb*TT/4, 256, 0, stream>>>(sim, b0, hsrc, rnorm, topidx, botidx, bcnt);
      else if (r == 1) k_topk<8,4><<<nb*TT/4, 256, 0, stream>>>(sim, b0, hsrc, rnorm, topidx, botidx, bcnt);
      else             k_topk<16,8><<<nb*TT/4, 256, 0, stream>>>(sim, b0, hsrc, rnorm, topidx, botidx, bcnt);
    }
    k_agg<<<BB*TT, 256, 0, stream>>>(hsrc, hdst, topidx, botidx, bcnt,
                                     gain + (size_t)r*DD, bias + (size_t)r*DD,
                                     log_mix, log_alpha, log_mom, r, ks[r]);
    if (r == 0){ hsrc = hB; hdst = hA; }
    else if (r == 1){ hsrc = hA; hdst = hB; }
  }
  k_final<<<(BB*TT*DD)/256, 256, 0, stream>>>(hB, x, log_scale, (float*)d_out, BB*TT*DD);
}

// Round 5
// 549.965 us; speedup vs baseline: 2.1238x; 1.4172x over previous
//
#include <hip/hip_runtime.h>
#include <hip/hip_bf16.h>
#include <cstdint>
#include <cstddef>

#define BB 4
#define TT 2048
#define DD 512
#define NEG_INF (-3.402823466e+38f)
#define POS_INF (3.402823466e+38f)

typedef __attribute__((ext_vector_type(8))) short bf16x8;
typedef __attribute__((ext_vector_type(8))) unsigned short ushort8;
typedef __attribute__((ext_vector_type(4))) float f32x4;

__device__ __forceinline__ float sigmoidf_(float x){ return 1.0f/(1.0f+expf(-x)); }

__device__ __forceinline__ unsigned short f2bf(float x){
  __hip_bfloat16 b = __float2bfloat16(x);
  return *reinterpret_cast<unsigned short*>(&b);
}

// monotonic float<->uint map (no NaNs in sim values)
__device__ __forceinline__ unsigned int fwd_map(float f){
  unsigned int b = __float_as_uint(f);
  return b ^ ((b & 0x80000000u) ? 0xFFFFFFFFu : 0x80000000u);
}
__device__ __forceinline__ float inv_map(unsigned int u){
  unsigned int b = (u & 0x80000000u) ? (u ^ 0x80000000u) : ~u;
  return __uint_as_float(b);
}

// ---------------- rnorm + bf16 hi/lo split of xn ----------------
__global__ __launch_bounds__(64) void k_normsplit(const float* __restrict__ h, float* __restrict__ rnorm,
                                                  unsigned short* __restrict__ Xh, unsigned short* __restrict__ Xl){
  int row = blockIdx.x;
  const float* hr = h + (size_t)row*DD;
  int lane = threadIdx.x;
  float4 v0 = *(const float4*)&hr[lane*4];
  float4 v1 = *(const float4*)&hr[lane*4 + 256];
  float ss = v0.x*v0.x+v0.y*v0.y+v0.z*v0.z+v0.w*v0.w
           + v1.x*v1.x+v1.y*v1.y+v1.z*v1.z+v1.w*v1.w;
  #pragma unroll
  for (int off=32; off; off>>=1) ss += __shfl_xor(ss, off);
  float rn = 1.0f / fmaxf(sqrtf(ss), 1e-12f);
  if (lane==0) rnorm[row] = rn;

  float xs[8] = {v0.x,v0.y,v0.z,v0.w,v1.x,v1.y,v1.z,v1.w};
  unsigned short hb[8], lb[8];
  #pragma unroll
  for (int q=0;q<8;q++){
    float xn = xs[q]*rn;
    unsigned short hh = f2bf(xn);
    __hip_bfloat16 bh = *reinterpret_cast<__hip_bfloat16*>(&hh);
    float rem = xn - __bfloat162float(bh);
    hb[q] = hh; lb[q] = f2bf(rem);
  }
  ushort4 h0 = {hb[0],hb[1],hb[2],hb[3]}, h1 = {hb[4],hb[5],hb[6],hb[7]};
  ushort4 l0 = {lb[0],lb[1],lb[2],lb[3]}, l1 = {lb[4],lb[5],lb[6],lb[7]};
  *(ushort4*)&Xh[(size_t)row*DD + lane*4]       = h0;
  *(ushort4*)&Xh[(size_t)row*DD + lane*4 + 256] = h1;
  *(ushort4*)&Xl[(size_t)row*DD + lane*4]       = l0;
  *(ushort4*)&Xl[(size_t)row*DD + lane*4 + 256] = l1;
}

// ---------------- sim via MFMA bf16 3-pass split, 128x128 tile ----------------
__global__ __launch_bounds__(256) void k_sim(const unsigned short* __restrict__ Xh,
                                             const unsigned short* __restrict__ Xl,
                                             float* __restrict__ sim, int b0){
  int p = blockIdx.x;
  int jt = (int)((sqrtf(8.0f*(float)p + 1.0f) - 1.0f)*0.5f);
  while ((jt+1)*(jt+2)/2 <= p) jt++;
  while (jt*(jt+1)/2 > p) jt--;
  int is = p - jt*(jt+1)/2;

  int bl = blockIdx.y;
  size_t xoff = (size_t)(b0 + bl)*TT*DD;
  const unsigned short* XhB = Xh + xoff;
  const unsigned short* XlB = Xl + xoff;
  float* simb = sim + (size_t)bl*TT*TT;
  int t0 = jt*128, s0 = is*128;

  __shared__ __align__(16) short As[128*32];
  __shared__ __align__(16) short Bs[128*32];

  int tid = threadIdx.x, wave = tid>>6, lane = tid&63;
  int wr = wave>>1, wc = wave&1;

  int srow = tid>>2;
  int sc8  = (tid&3)*8;

  f32x4 acc[4][4];
  #pragma unroll
  for (int m=0;m<4;m++)
    #pragma unroll
    for (int n=0;n<4;n++) acc[m][n] = (f32x4){0.f,0.f,0.f,0.f};

  ushort8 ra0, ra1, rb0, rb1;
  auto gload = [&](int s){
    int pass = s>>4; int kcol = (s&15)*32;
    const unsigned short* sA = (pass<2) ? XhB : XlB;
    const unsigned short* sB = (pass!=1) ? XhB : XlB;
    ra0 = *(const ushort8*)&sA[(size_t)(t0+srow)*DD + kcol + sc8];
    ra1 = *(const ushort8*)&sA[(size_t)(t0+srow+64)*DD + kcol + sc8];
    rb0 = *(const ushort8*)&sB[(size_t)(s0+srow)*DD + kcol + sc8];
    rb1 = *(const ushort8*)&sB[(size_t)(s0+srow+64)*DD + kcol + sc8];
  };

  gload(0);
  for (int s=0; s<48; ++s){
    __syncthreads();
    *(ushort8*)&As[srow*32 + sc8]      = ra0;
    *(ushort8*)&As[(srow+64)*32 + sc8] = ra1;
    *(ushort8*)&Bs[srow*32 + sc8]      = rb0;
    *(ushort8*)&Bs[(srow+64)*32 + sc8] = rb1;
    __syncthreads();
    if (s < 47) gload(s+1);

    int arow = wr*64 + (lane&15);
    int brow = wc*64 + (lane&15);
    int kb = (lane>>4)*8;
    bf16x8 af[4], bf[4];
    #pragma unroll
    for (int m=0;m<4;m++) af[m] = *(const bf16x8*)&As[(arow + m*16)*32 + kb];
    #pragma unroll
    for (int n=0;n<4;n++) bf[n] = *(const bf16x8*)&Bs[(brow + n*16)*32 + kb];
    #pragma unroll
    for (int m=0;m<4;m++)
      #pragma unroll
      for (int n=0;n<4;n++)
        acc[m][n] = __builtin_amdgcn_mfma_f32_16x16x32_bf16(af[m], bf[n], acc[m][n], 0, 0, 0);
  }

  #pragma unroll
  for (int m=0;m<4;m++){
    int t = t0 + wr*64 + m*16 + (lane>>4)*4;
    #pragma unroll
    for (int n=0;n<4;n++){
      int sc = s0 + wc*64 + n*16 + (lane&15);
      float* dst = simb + (size_t)t*TT + sc;
      #pragma unroll
      for (int j=0;j<4;j++) dst[(size_t)j*TT] = acc[m][n][j];
    }
  }
}

// ---------------- top-k: block-per-row LDS radix select ----------------
template<int ESIM, int ECON>
__global__ __launch_bounds__(256) void k_topk(const float* __restrict__ sim, int b0,
                                              const float* __restrict__ h, const float* __restrict__ rnorm,
                                              int* __restrict__ topidx, int* __restrict__ botidx,
                                              int* __restrict__ bcnt){
  constexpr int K1 = ESIM + 8;
  constexpr float TAU = 5e-5f;
  __shared__ unsigned int s_u[TT];
  __shared__ int s_hist[256];
  __shared__ int s_cand[K1];
  __shared__ int s_eq[44];
  __shared__ int s_sel[ESIM];
  __shared__ int s_bot[ECON + 8];
  __shared__ unsigned int s_pfx;
  __shared__ int s_kp, s_ngt, s_neq;

  int tid = threadIdx.x, lane = tid & 63, wid = tid >> 6;
  int lrow = blockIdx.x;
  int bl = lrow >> 11, t = lrow & (TT-1);
  int gb = b0 + bl;
  int grow = (gb << 11) | t;

  if (t <= ESIM){               // all past elements selected; no bottoms possible
    if (tid < t) topidx[(size_t)grow*16 + tid] = tid;
    if (tid == 0) bcnt[grow] = 0;
    return;
  }
  const float* srow = sim + (size_t)lrow*TT;
  const float* hb  = h + (size_t)gb*TT*DD;
  const float* rnb = rnorm + (size_t)gb*TT;

  // stage row into LDS, monotonic-mapped
  for (int s = tid; s < t; s += 256) s_u[s] = fwd_map(srow[s]);
  int k1 = min(t, K1);
  if (tid == 0){ s_pfx = 0u; s_kp = k1; s_ngt = 0; s_neq = 0; }
  __syncthreads();

  // 4-pass radix select: find exact value of k1-th largest
  for (int pass = 0; pass < 4; ++pass){
    int shift = 24 - 8*pass;
    unsigned int keep = (pass == 0) ? 0u : (0xFFFFFFFFu << (shift + 8));
    unsigned int pfx = s_pfx; int kp = s_kp;
    s_hist[tid] = 0;
    __syncthreads();
    for (int s = tid; s < t; s += 256){
      unsigned int u = s_u[s];
      if (((u ^ pfx) & keep) == 0)
        atomicAdd(&s_hist[(u >> shift) & 255], 1);
    }
    __syncthreads();
    if (wid == 0){
      int m4 = s_hist[4*lane] + s_hist[4*lane+1] + s_hist[4*lane+2] + s_hist[4*lane+3];
      int x = __shfl(m4, 63 - lane);
      #pragma unroll
      for (int off = 1; off < 64; off <<= 1){
        int v = __shfl_up(x, off);
        if (lane >= off) x += v;
      }
      int T = __shfl(x, 63 - lane);     // inclusive suffix sum over digit-groups
      int G = T - m4;                   // count in strictly-greater groups
      bool hit = (G < kp) && (kp <= T);
      if (hit){
        int c = G; int D = 4*lane;
        #pragma unroll
        for (int i = 3; i >= 0; --i){
          int hc = s_hist[4*lane + i];
          if (kp <= c + hc){ D = 4*lane + i; break; }
          c += hc;
        }
        s_pfx = pfx | ((unsigned int)D << shift);
        s_kp = kp - c;
      }
    }
    __syncthreads();
  }
  unsigned int uthr = s_pfx;

  // collect candidates: u > uthr (count < k1 guaranteed) and ties u == uthr
  for (int s = tid; s < t; s += 256){
    unsigned int u = s_u[s];
    if (u > uthr){
      int p = atomicAdd(&s_ngt, 1);
      s_cand[p] = s;
    } else if (u == uthr){
      int p = atomicAdd(&s_neq, 1);
      if (p < 44) s_eq[p] = s;
    }
  }
  __syncthreads();
  if (wid != 0) return;                 // wave 0 finishes the row (no barriers below)

  int c_gt = s_ngt;
  int c_eq = min(s_neq, 44);
  int ncand = min(c_gt + c_eq, 64);

  unsigned int myu = 0u; int myi = 0x7fffffff;
  if (lane < ncand){
    myi = (lane < c_gt) ? s_cand[lane] : s_eq[lane - c_gt];
    myu = s_u[myi];
  }

  // extract top ESIM+1 by (u desc, idx asc)
  float vA = 0.f, vB = 0.f;
  {
    unsigned int cu = myu; int ci = myi;
    #pragma unroll
    for (int k = 0; k <= ESIM; ++k){
      unsigned int bu = cu; int bi = ci;
      #pragma unroll
      for (int off=32; off; off>>=1){
        unsigned int ou = __shfl_xor(bu, off); int oi = __shfl_xor(bi, off);
        if (ou > bu || (ou == bu && oi < bi)){ bu = ou; bi = oi; }
      }
      if (k < ESIM && lane == 0) s_sel[k] = bi;
      if (k == ESIM-1) vA = inv_map(bu);
      if (k == ESIM)   vB = inv_map(bu);
      if (ci == bi){ cu = 0u; ci = 0x7fffffff; }
    }
  }

  bool resc = (vA - vB < TAU);
  if (resc){
    // exact fp32 rescore of all candidates
    const float* hq = hb + (size_t)t*DD;
    float rt = rnb[t];
    float4 q0 = *(const float4*)&hq[lane*4];
    float4 q1 = *(const float4*)&hq[lane*4 + 256];
    float ev = NEG_INF;
    for (int j = 0; j < ncand; ++j){
      int idx = (j < c_gt) ? s_cand[j] : s_eq[j - c_gt];
      const float* hc = hb + (size_t)idx*DD;
      float4 c0 = *(const float4*)&hc[lane*4];
      float4 c1 = *(const float4*)&hc[lane*4 + 256];
      float pp = q0.x*c0.x+q0.y*c0.y+q0.z*c0.z+q0.w*c0.w
               + q1.x*c1.x+q1.y*c1.y+q1.z*c1.z+q1.w*c1.w;
      #pragma unroll
      for (int off=32; off; off>>=1) pp += __shfl_xor(pp, off);
      float ex = pp * rt * rnb[idx];
      if (lane == j) ev = ex;
    }
    float rv = (lane < ncand) ? ev : NEG_INF;
    int   ri = myi;
    #pragma unroll
    for (int k = 0; k < ESIM; ++k){
      float bv = rv; int bi = ri;
      #pragma unroll
      for (int off=32; off; off>>=1){
        float ov = __shfl_xor(bv, off); int oi = __shfl_xor(bi, off);
        if (ov > bv || (ov == bv && oi < bi)){ bv = ov; bi = oi; }
      }
      if (lane == 0) s_sel[k] = bi;
      if (ri == bi) rv = NEG_INF;
    }
  }
  if (lane < ESIM) topidx[(size_t)grow*16 + lane] = s_sel[lane];

  // ---- bottoms: rows with t > TT - ECON only (<=7 per batch) ----
  int need = ECON - (TT - t);
  int cnt = 0;
  if (need > 0){
    if (lane < ESIM) s_u[s_sel[lane]] = 0xFFFFFFFFu;   // exclude top set
    int nb_ext = min(need + 8, t - ESIM);
    float wA = 0.f, wB = 0.f;
    for (int k = 0; k < nb_ext; ++k){
      unsigned int mu = 0xFFFFFFFFu; int mi = 0x7fffffff;
      for (int s = lane; s < t; s += 64){
        unsigned int u = s_u[s];
        if (u < mu || (u == mu && s < mi)){ mu = u; mi = s; }
      }
      #pragma unroll
      for (int off=32; off; off>>=1){
        unsigned int ou = __shfl_xor(mu, off); int oi = __shfl_xor(mi, off);
        if (ou < mu || (ou == mu && oi < mi)){ mu = ou; mi = oi; }
      }
      if (lane == 0){ s_bot[k] = mi; s_u[mi] = 0xFFFFFFFFu; }
      if (k == need-1) wA = inv_map(mu);
      if (k == need)   wB = inv_map(mu);
    }
    cnt = need;
    bool rb = (nb_ext > need) && (wB - wA < TAU);
    if (!rb){
      if (lane < need) botidx[(size_t)grow*8 + lane] = s_bot[lane];
    } else {
      const float* hq = hb + (size_t)t*DD;
      float rt = rnb[t];
      float4 q0 = *(const float4*)&hq[lane*4];
      float4 q1 = *(const float4*)&hq[lane*4 + 256];
      float ev = POS_INF; int ei = 0x7fffffff;
      for (int j = 0; j < nb_ext; ++j){
        int idx = s_bot[j];
        const float* hc = hb + (size_t)idx*DD;
        float4 c0 = *(const float4*)&hc[lane*4];
        float4 c1 = *(const float4*)&hc[lane*4 + 256];
        float pp = q0.x*c0.x+q0.y*c0.y+q0.z*c0.z+q0.w*c0.w
                 + q1.x*c1.x+q1.y*c1.y+q1.z*c1.z+q1.w*c1.w;
        #pragma unroll
        for (int off=32; off; off>>=1) pp += __shfl_xor(pp, off);
        float ex = pp * rt * rnb[idx];
        if (lane == j){ ev = ex; ei = idx; }
      }
      #pragma unroll
      for (int k = 0; k < ECON; ++k){
        if (k < need){
          float bv = ev; int bi = ei;
          #pragma unroll
          for (int off=32; off; off>>=1){
            float ov = __shfl_xor(bv, off); int oi = __shfl_xor(bi, off);
            if (ov < bv || (ov == bv && oi < bi)){ bv = ov; bi = oi; }
          }
          if (lane == 0) botidx[(size_t)grow*8 + k] = bi;
          if (ei == bi) ev = POS_INF;
        }
      }
    }
  }
  if (lane == 0) bcnt[grow] = cnt;
}

// ---------------- aggregate + blend + gelu + momentum ----------------
__global__ __launch_bounds__(256) void k_agg(const float* __restrict__ hsrc, float* __restrict__ hdst,
                                             const int* __restrict__ topidx, const int* __restrict__ botidx,
                                             const int* __restrict__ bcnt,
                                             const float* __restrict__ gain, const float* __restrict__ bias,
                                             const float* __restrict__ log_mix, const float* __restrict__ log_alpha,
                                             const float* __restrict__ log_momentum, int r, int eff_sim){
  int row = blockIdx.x;
  int b = row >> 11; int t = row & (TT-1);
  int n_sim = min(eff_sim, t);
  int n_con = bcnt[row];
  float mix      = sigmoidf_(log_mix[r]);
  float alpha    = sigmoidf_(log_alpha[r]);
  float momentum = sigmoidf_(log_momentum[0]);
  const float* hb = hsrc + (size_t)b*TT*DD;

  __shared__ int sidx[16];
  __shared__ int scidx[8];
  if (threadIdx.x < 16) sidx[threadIdx.x]  = (threadIdx.x < n_sim) ? topidx[(size_t)row*16 + threadIdx.x] : 0;
  if (threadIdx.x < 8)  scidx[threadIdx.x] = (threadIdx.x < n_con) ? botidx[(size_t)row*8  + threadIdx.x] : 0;
  __syncthreads();

  #pragma unroll
  for (int e = threadIdx.x; e < DD; e += 256){
    float sp = 0.f;
    for (int j=0;j<n_sim;j++) sp += hb[(size_t)sidx[j]*DD + e];
    float sn = 0.f;
    for (int j=0;j<n_con;j++) sn += hb[(size_t)scidx[j]*DD + e];
    float mp = sp / (float)max(n_sim, 1);
    float mn = sn / (float)max(n_con, 1);
    float ctx = alpha*mp + (1.f-alpha)*mn;
    float hv = hsrc[(size_t)row*DD + e];
    float blended = mix*hv + (1.f-mix)*ctx;
    float u = blended*gain[e] + bias[e];
    float g = 0.5f*u*(1.0f + erff(u*0.7071067811865475f));
    hdst[(size_t)row*DD + e] = momentum*hv + (1.f-momentum)*g;
  }
}

// ---------------- out = (h - x) * scale ----------------
__global__ __launch_bounds__(256) void k_final(const float* __restrict__ hfin, const float* __restrict__ x,
                                               const float* __restrict__ log_scale, float* __restrict__ out, int n){
  float scale = log1pf(expf(log_scale[0])) + 0.01f;
  int i = blockIdx.x*256 + threadIdx.x;
  if (i < n) out[i] = (hfin[i] - x[i]) * scale;
}

extern "C" void kernel_launch(void* const* d_in, const int* in_sizes, int n_in,
                              void* d_out, int out_size, void* d_ws, size_t ws_size,
                              hipStream_t stream) {
  const float* x         = (const float*)d_in[0];
  const float* gain      = (const float*)d_in[1];
  const float* bias      = (const float*)d_in[2];
  const float* log_mix   = (const float*)d_in[3];
  const float* log_alpha = (const float*)d_in[4];
  const float* log_mom   = (const float*)d_in[5];
  const float* log_scale = (const float*)d_in[6];

  float* hA = (float*)d_out;
  char* ws = (char*)d_ws;
  size_t off = 0;
  auto alloc = [&](size_t bytes){ void* p = ws + off; off += (bytes + 255) & ~(size_t)255; return p; };

  float*          hB     = (float*)alloc((size_t)BB*TT*DD*4);
  float*          rnorm  = (float*)alloc((size_t)BB*TT*4);
  int*            topidx = (int*)  alloc((size_t)BB*TT*16*4);
  int*            botidx = (int*)  alloc((size_t)BB*TT*8*4);
  int*            bcnt   = (int*)  alloc((size_t)BB*TT*4);
  unsigned short* Xh     = (unsigned short*)alloc((size_t)BB*TT*DD*2);
  unsigned short* Xl     = (unsigned short*)alloc((size_t)BB*TT*DD*2);

  size_t rem = (ws_size > off) ? (ws_size - off) : 0;
  int cb = (int)(rem / ((size_t)TT*TT*4));
  if (cb < 1) cb = 1;
  if (cb > BB) cb = BB;
  float* sim = (float*)alloc((size_t)cb*TT*TT*4);

  const float* hsrc = x;
  float* hdst = hB;
  const int ks[3] = {4, 8, 16};

  for (int r = 0; r < 3; ++r){
    k_normsplit<<<BB*TT, 64, 0, stream>>>(hsrc, rnorm, Xh, Xl);
    for (int b0 = 0; b0 < BB; b0 += cb){
      int nb = (BB - b0 < cb) ? (BB - b0) : cb;
      dim3 g(136, nb);
      k_sim<<<g, 256, 0, stream>>>(Xh, Xl, sim, b0);
      if (r == 0)      k_topk<4,2><<<nb*TT, 256, 0, stream>>>(sim, b0, hsrc, rnorm, topidx, botidx, bcnt);
      else if (r == 1) k_topk<8,4><<<nb*TT, 256, 0, stream>>>(sim, b0, hsrc, rnorm, topidx, botidx, bcnt);
      else             k_topk<16,8><<<nb*TT, 256, 0, stream>>>(sim, b0, hsrc, rnorm, topidx, botidx, bcnt);
    }
    k_agg<<<BB*TT, 256, 0, stream>>>(hsrc, hdst, topidx, botidx, bcnt,
                                     gain + (size_t)r*DD, bias + (size_t)r*DD,
                                     log_mix, log_alpha, log_mom, r, ks[r]);
    if (r == 0){ hsrc = hB; hdst = hA; }
    else if (r == 1){ hsrc = hA; hdst = hB; }
  }
  k_final<<<(BB*TT*DD)/256, 256, 0, stream>>>(hB, x, log_scale, (float*)d_out, BB*TT*DD);
}